// Round 1
// baseline (330.967 us; speedup 1.0000x reference)
//
#include <hip/hip_runtime.h>

#define E_EDGES 800000
#define NN 50000
#define OUT_STRIDE 288

typedef __bf16 bf16;
typedef bf16 bf16x8 __attribute__((ext_vector_type(8)));
typedef float floatx4 __attribute__((ext_vector_type(4)));
typedef unsigned short ushort8v __attribute__((ext_vector_type(8)));

__device__ __forceinline__ unsigned short f2bf(float f){
    // native RNE convert (compiler emits v_cvt_pk_bf16_f32 on gfx950)
    return __builtin_bit_cast(unsigned short, (bf16)f);
}
__device__ __forceinline__ unsigned pack2bf(float a, float b){
    unsigned short lo = __builtin_bit_cast(unsigned short, (bf16)a);
    unsigned short hi = __builtin_bit_cast(unsigned short, (bf16)b);
    return (unsigned)lo | ((unsigned)hi << 16);
}
// monotone float<->uint for atomicMax/Min
__device__ __forceinline__ unsigned encf(float f){
    unsigned u = __float_as_uint(f);
    return (u & 0x80000000u) ? ~u : (u | 0x80000000u);
}
__device__ __forceinline__ float decf(unsigned u){
    return __uint_as_float((u & 0x80000000u) ? (u ^ 0x80000000u) : ~u);
}
__device__ __forceinline__ floatx4 mfma16(ushort8v a, ushort8v b, floatx4 c){
    return __builtin_amdgcn_mfma_f32_16x16x32_bf16(
        __builtin_bit_cast(bf16x8, a), __builtin_bit_cast(bf16x8, b), c, 0, 0, 0);
}
__device__ __forceinline__ void flush_run(float* out, int node, float s, float mx, float mn, int lane){
    float* sp = out + (long)node * OUT_STRIDE + 64;
    atomicAdd(sp + lane, s);
    atomicMax((unsigned*)sp + 64 + lane, encf(mx));
    atomicMin((unsigned*)sp + 128 + lane, encf(mn));
}

// ---------------- setup: init out accum | x->bf16 | prepack weights | hist ----------------
// cnt is zeroed by hipMemsetAsync before this kernel, so hist atomics can live here.
#define INIT_N 2400000
#define XBF_N  800000
#define PK_N   40960
#define HIST_BASE (INIT_N + XBF_N + PK_N)
#define SETUP_TOTAL (HIST_BASE + E_EDGES)

__global__ void setup_kernel(const float* __restrict__ x, const int* __restrict__ ei,
                             const float* __restrict__ W1, const float* __restrict__ W2,
                             const float* __restrict__ W3,
                             unsigned short* __restrict__ wp, unsigned short* __restrict__ xbf,
                             int* __restrict__ cnt, float* __restrict__ out)
{
    int i = blockIdx.x * blockDim.x + threadIdx.x;
    if (i < INIT_N) {
        // out row: [x 0..16 | sum 16..32 | max 32..48 | min 48..64 | u 64..72] uint4 units
        int row = i / 48, q = i % 48;
        uint4 val = (q < 32) ? make_uint4(0u, 0u, 0u, 0u)
                             : make_uint4(~0u, ~0u, ~0u, ~0u);
        ((uint4*)out)[(long)row * 72 + 16 + q] = val;
        return;
    }
    i -= INIT_N;
    if (i < XBF_N) {
        float4 v = ((const float4*)x)[i];
        ushort4 o; o.x = f2bf(v.x); o.y = f2bf(v.y); o.z = f2bf(v.z); o.w = f2bf(v.w);
        ((ushort4*)xbf)[i] = o;
        return;
    }
    i -= XBF_N;
    if (i < PK_N) {
        // A-fragment pack (weights as A): wp[f*8+j] = W[kc*32+quad*8+j][nt*16+ln]
        const float* W; int N; int idx;
        if (i < 16384)      { W = W1; N = 128; idx = i; }
        else if (i < 32768) { W = W2; N = 128; idx = i - 16384; }
        else                { W = W3; N = 64;  idx = i - 32768; }
        int j = idx & 7, lane = (idx >> 3) & 63, kc = (idx >> 9) & 3, nt = idx >> 11;
        wp[i] = f2bf(W[(kc * 32 + ((lane >> 4) & 3) * 8 + j) * N + nt * 16 + (lane & 15)]);
        return;
    }
    i -= PK_N;
    if (i < E_EDGES) atomicAdd(&cnt[ei[E_EDGES + i]], 1);
}

// ---------------- counting sort by destination ----------------
// scanA: 256 blocks x 256 thr, 196 nodes/block -> local exclusive + block sums
__global__ void scanA_kernel(const int* __restrict__ cnt, int* __restrict__ off,
                             int* __restrict__ bsum){
    __shared__ int s[256];
    int tid = threadIdx.x;
    int node = blockIdx.x * 196 + tid;
    int val = (tid < 196 && node < NN) ? cnt[node] : 0;
    s[tid] = val;
    __syncthreads();
    for (int d = 1; d < 256; d <<= 1){
        int t = (tid >= d) ? s[tid - d] : 0;
        __syncthreads();
        s[tid] += t;
        __syncthreads();
    }
    if (tid < 196 && node < NN) off[node] = s[tid] - val;  // local exclusive
    if (tid == 255) bsum[blockIdx.x] = s[255];             // block total
}

// scanB: 1 block x 256 thr, exclusive-scan bsum -> bbase
__global__ void scanB_kernel(const int* __restrict__ bsum, int* __restrict__ bbase){
    __shared__ int s[256];
    int tid = threadIdx.x;
    int val = bsum[tid];
    s[tid] = val;
    __syncthreads();
    for (int d = 1; d < 256; d <<= 1){
        int t = (tid >= d) ? s[tid - d] : 0;
        __syncthreads();
        s[tid] += t;
        __syncthreads();
    }
    bbase[tid] = s[tid] - val;  // exclusive
}

// scatter (+ fused scanC): global pos = local excl + block base
__global__ void scatter_kernel(const int* __restrict__ ei, int* __restrict__ off,
                               const int* __restrict__ bbase, int2* __restrict__ enodes){
    int e = blockIdx.x * blockDim.x + threadIdx.x;
    if (e >= E_EDGES) return;
    int c = ei[E_EDGES + e], r = ei[e];
    int pos = atomicAdd(&off[c], 1) + bbase[c / 196];
    enodes[pos] = make_int2(r, c);
}

// ---------------- edge MLP: 32 edges per wave-tile, barrier-free ----------------
// Weight fragments are read from global (L2-resident). Flat step index 0..19
// (L1: 0..7, L2: 8..15, L3: 16..19), triple-buffered with distance-2 prefetch
// so the ~200-400cy L2 latency hides under the previous steps' MFMAs.
__global__ __launch_bounds__(256, 4) void edge_mlp_kernel(
    const unsigned short* __restrict__ xbf, const int2* __restrict__ enodes,
    const unsigned short* __restrict__ wp,
    const float* __restrict__ b1, const float* __restrict__ b2, const float* __restrict__ b3,
    float* __restrict__ out)
{
    __shared__ __align__(16) unsigned char smem[4 * 8704];

    const int tid  = threadIdx.x;
    const int lane = tid & 63;
    const int w    = tid >> 6;
    const int quad = lane >> 4;
    const int ln   = lane & 15;
    unsigned short* wbuf = (unsigned short*)(smem + w * 8704);  // 32 rows x 136 u16
    float* Tf = (float*)wbuf;                                    // 64 rows x 33 f32
    const ushort8v* wpv = (const ushort8v*)wp;

    const int g = blockIdx.x * 4 + w;       // tile id, 25000 total
    const int ebase = g * 32;
    int2 ed0 = enodes[ebase + ln];
    int2 ed1 = enodes[ebase + 16 + ln];

    // rotating weight-fragment buffers (statically indexed after unroll)
    ushort8v Wb[3][4];
#define LDW(slot, idx) { _Pragma("unroll") for (int _k = 0; _k < 4; _k++) \
        Wb[slot][_k] = wpv[(idx) * 256 + _k * 64 + lane]; }

    LDW(0, 0)
    LDW(1, 1)

    const ushort8v* r0 = (const ushort8v*)(xbf + (long)ed0.x * 64);
    const ushort8v* c0 = (const ushort8v*)(xbf + (long)ed0.y * 64);
    const ushort8v* r1 = (const ushort8v*)(xbf + (long)ed1.x * 64);
    const ushort8v* c1 = (const ushort8v*)(xbf + (long)ed1.y * 64);
    ushort8v B0[4] = { r0[quad], r0[4 + quad], c0[quad], c0[4 + quad] };
    ushort8v B1[4] = { r1[quad], r1[4 + quad], c1[quad], c1[4 + quad] };

    // ---- layer 1: D[och][edge] -> wbuf[edge][och] bf16 ----
#pragma unroll
    for (int nt = 0; nt < 8; nt++){
        LDW((nt + 2) % 3, nt + 2)                      // idx 2..9 (8,9 = L2 sets 0,1)
        floatx4 bini = *(const floatx4*)(b1 + nt * 16 + quad * 4);
        floatx4 a0 = bini, a1 = bini;
#pragma unroll
        for (int kc = 0; kc < 4; kc++){
            a0 = mfma16(Wb[nt % 3][kc], B0[kc], a0);
            a1 = mfma16(Wb[nt % 3][kc], B1[kc], a1);
        }
        uint2 p0, p1;
        p0.x = pack2bf(fmaxf(a0[0], 0.f), fmaxf(a0[1], 0.f));
        p0.y = pack2bf(fmaxf(a0[2], 0.f), fmaxf(a0[3], 0.f));
        p1.x = pack2bf(fmaxf(a1[0], 0.f), fmaxf(a1[1], 0.f));
        p1.y = pack2bf(fmaxf(a1[2], 0.f), fmaxf(a1[3], 0.f));
        int col = nt * 16 + quad * 4;
        *(uint2*)(wbuf + ln * 136 + col)        = p0;
        *(uint2*)(wbuf + (16 + ln) * 136 + col) = p1;
    }

    // ---- layer 2: preload B-frags, in-place ----
    ushort8v H0[4], H1[4];
#pragma unroll
    for (int kc = 0; kc < 4; kc++){
        H0[kc] = *(const ushort8v*)(wbuf + ln * 136 + kc * 32 + quad * 8);
        H1[kc] = *(const ushort8v*)(wbuf + (16 + ln) * 136 + kc * 32 + quad * 8);
    }
#pragma unroll
    for (int nt = 0; nt < 8; nt++){
        LDW((8 + nt + 2) % 3, 8 + nt + 2)              // idx 10..17 (16,17 = L3 sets 0,1)
        floatx4 bini = *(const floatx4*)(b2 + nt * 16 + quad * 4);
        floatx4 a0 = bini, a1 = bini;
#pragma unroll
        for (int kc = 0; kc < 4; kc++){
            a0 = mfma16(Wb[(8 + nt) % 3][kc], H0[kc], a0);
            a1 = mfma16(Wb[(8 + nt) % 3][kc], H1[kc], a1);
        }
        uint2 p0, p1;
        p0.x = pack2bf(fmaxf(a0[0], 0.f), fmaxf(a0[1], 0.f));
        p0.y = pack2bf(fmaxf(a0[2], 0.f), fmaxf(a0[3], 0.f));
        p1.x = pack2bf(fmaxf(a1[0], 0.f), fmaxf(a1[1], 0.f));
        p1.y = pack2bf(fmaxf(a1[2], 0.f), fmaxf(a1[3], 0.f));
        int col = nt * 16 + quad * 4;
        *(uint2*)(wbuf + ln * 136 + col)        = p0;
        *(uint2*)(wbuf + (16 + ln) * 136 + col) = p1;
    }

    // ---- layer 3: f32 T[och][edge], LD=33 ----
    ushort8v G0[4], G1[4];
#pragma unroll
    for (int kc = 0; kc < 4; kc++){
        G0[kc] = *(const ushort8v*)(wbuf + ln * 136 + kc * 32 + quad * 8);
        G1[kc] = *(const ushort8v*)(wbuf + (16 + ln) * 136 + kc * 32 + quad * 8);
    }
#pragma unroll
    for (int nt = 0; nt < 4; nt++){
        if (nt < 2) LDW((16 + nt + 2) % 3, 16 + nt + 2)   // idx 18,19
        floatx4 bini = *(const floatx4*)(b3 + nt * 16 + quad * 4);
        floatx4 a0 = bini, a1 = bini;
#pragma unroll
        for (int kc = 0; kc < 4; kc++){
            a0 = mfma16(Wb[(16 + nt) % 3][kc], G0[kc], a0);
            a1 = mfma16(Wb[(16 + nt) % 3][kc], G1[kc], a1);
        }
        int och = nt * 16 + quad * 4;
#pragma unroll
        for (int r = 0; r < 4; r++){
            Tf[(och + r) * 33 + ln]      = a0[r];
            Tf[(och + r) * 33 + 16 + ln] = a1[r];
        }
    }

    // ---- epilogue: lane = channel, run-reduce over 32 sorted edges ----
    float v[32];
#pragma unroll
    for (int j = 0; j < 32; j++) v[j] = Tf[lane * 33 + j];
    int cn0 = ed0.y, cn1 = ed1.y;
    int cur = __builtin_amdgcn_readlane(cn0, 0);
    float s = v[0], mx = v[0], mn = v[0];
#pragma unroll
    for (int j = 1; j < 32; j++){
        int nj = (j < 16) ? __builtin_amdgcn_readlane(cn0, j)
                          : __builtin_amdgcn_readlane(cn1, j - 16);
        if (nj != cur){
            flush_run(out, cur, s, mx, mn, lane);
            cur = nj; s = v[j]; mx = v[j]; mn = v[j];
        } else {
            s += v[j]; mx = fmaxf(mx, v[j]); mn = fminf(mn, v[j]);
        }
    }
    flush_run(out, cur, s, mx, mn, lane);
}

// ---------------- finalize ----------------
__global__ void finalize_kernel(const float* __restrict__ x, const float* __restrict__ u,
                                const int* __restrict__ batch, const int* __restrict__ cnt,
                                float* __restrict__ out)
{
    long i = (long)blockIdx.x * blockDim.x + threadIdx.x;
    if (i >= (long)NN * 72) return;
    int ndx = (int)(i / 72);
    int q   = (int)(i % 72);
    float4 res;
    if (q < 16) {
        res = ((const float4*)(x + (long)ndx * 64))[q];
    } else if (q < 32) {
        float4 sv = ((const float4*)out)[i];
        int k = cnt[ndx];
        float inv = 1.f / (float)(k > 0 ? k : 1);
        res.x = sv.x * inv; res.y = sv.y * inv; res.z = sv.z * inv; res.w = sv.w * inv;
    } else if (q < 64) {
        uint4 e = ((const uint4*)out)[i];
        bool ne = cnt[ndx] > 0;
        res.x = ne ? decf(e.x) : 0.f; res.y = ne ? decf(e.y) : 0.f;
        res.z = ne ? decf(e.z) : 0.f; res.w = ne ? decf(e.w) : 0.f;
    } else {
        res = ((const float4*)(u + (long)batch[ndx] * 32))[q - 64];
    }
    ((float4*)out)[i] = res;
}

extern "C" void kernel_launch(void* const* d_in, const int* in_sizes, int n_in,
                              void* d_out, int out_size, void* d_ws, size_t ws_size,
                              hipStream_t stream)
{
    const float* x     = (const float*)d_in[0];
    const int*   ei    = (const int*)d_in[1];
    // d_in[2] = edge_attr (unused)
    const float* u     = (const float*)d_in[3];
    const int*   batch = (const int*)d_in[4];
    const float* W1    = (const float*)d_in[5];
    const float* b1    = (const float*)d_in[6];
    const float* W2    = (const float*)d_in[7];
    const float* b2    = (const float*)d_in[8];
    const float* W3    = (const float*)d_in[9];
    const float* b3    = (const float*)d_in[10];
    float* out = (float*)d_out;
    unsigned char* ws = (unsigned char*)d_ws;

    // ws layout (16B-aligned)
    unsigned short* wp     = (unsigned short*)ws;              //    81,920 B
    int*            cnt    = (int*)(ws + 81920);               //   200,000 B
    int*            off    = (int*)(ws + 281920);              //   200,000 B
    int*            bsum   = (int*)(ws + 481920);              //     1,024 B
    int*            bbase  = (int*)(ws + 482944);              //     1,024 B
    int2*           enodes = (int2*)(ws + 483968);             // 6,400,000 B
    unsigned short* xbf    = (unsigned short*)(ws + 6883968);  // 6,400,000 B

    hipMemsetAsync(cnt, 0, 200000, stream);
    setup_kernel<<<(SETUP_TOTAL + 255) / 256, 256, 0, stream>>>(x, ei, W1, W2, W3, wp, xbf, cnt, out);
    scanA_kernel<<<256, 256, 0, stream>>>(cnt, off, bsum);
    scanB_kernel<<<1, 256, 0, stream>>>(bsum, bbase);
    scatter_kernel<<<(E_EDGES + 255) / 256, 256, 0, stream>>>(ei, off, bbase, enodes);
    edge_mlp_kernel<<<6250, 256, 0, stream>>>(xbf, enodes, wp, b1, b2, b3, out);
    finalize_kernel<<<(int)(((long)NN * 72 + 255) / 256), 256, 0, stream>>>(x, u, batch, cnt, out);
}